// Round 1
// baseline (666.720 us; speedup 1.0000x reference)
//
#include <hip/hip_runtime.h>

// ---------------- transposed-weight workspace layout (floats) ----------------
#define OFF_MSG1T 0        // [67][32] = 2144
#define OFF_MSG2T 2144     // [32][32] = 1024
#define OFF_GR    3168     // [64][32] = 2048  (k<32: w_ih rows 0..31 ; k>=32: w_hh rows 0..31)
#define OFF_GZ    5216     // [64][32] = 2048  (rows 32..63)
#define OFF_GN    7264     // [64][32] = 2048  (rows 64..95)
#define OFF_BR    9312     // [32] b_ih+b_hh (r)
#define OFF_BZ    9344     // [32] (z)
#define OFF_WC    9376     // [32][32] folded (Wo@Wv)^T
#define OFF_BC    10400    // [32] Wo@bv+bo
#define OFF_E1    10432    // [34][32]
#define OFF_E2    11520    // [32][32]
#define OFF_C1    12544    // [32][32]
#define WS_FLOATS 13568

#define EDGE_WORKERS 4096
#define COPY_WORKERS 2048
#define BLK 128

__device__ __forceinline__ float sigf(float v) { return 1.0f / (1.0f + __expf(-v)); }
__device__ __forceinline__ float tanhf_fast(float v) {
    float a = fabsf(v);
    float t = __expf(-2.0f * a);
    float r = (1.0f - t) / (1.0f + t);
    return v < 0.0f ? -r : r;
}

// acc[j] += xs_col[k*128] * WT[(k-K0)*32 + j]   (weights wave-uniform -> s_load)
template <int K0, int K1>
__device__ __forceinline__ void pass(float* acc, const float* __restrict__ WT,
                                     const float* xcol) {
#pragma unroll 2
    for (int k = K0; k < K1; ++k) {
        float xk = xcol[k * 128];
        const float* w = &WT[(k - K0) * 32];
#pragma unroll
        for (int j = 0; j < 32; ++j) acc[j] = fmaf(xk, w[j], acc[j]);
    }
}

__global__ void winner_k(const int* __restrict__ dst_ids, int* __restrict__ winner, int E) {
    int e = blockIdx.x * 256 + threadIdx.x;
    if (e < E) atomicMax(winner + dst_ids[e], e + 1);
}

__global__ void prep_k(const float* __restrict__ msg_W1, const float* __restrict__ msg_W2,
                       const float* __restrict__ w_ih, const float* __restrict__ b_ih,
                       const float* __restrict__ w_hh, const float* __restrict__ b_hh,
                       const float* __restrict__ Wv, const float* __restrict__ bv,
                       const float* __restrict__ Wo, const float* __restrict__ bo,
                       const float* __restrict__ emb_W1, const float* __restrict__ emb_W2,
                       const float* __restrict__ cls_W1, float* __restrict__ WS) {
    int t = threadIdx.x;  // 256 threads, 1 block
    for (int i = t; i < 67 * 32; i += 256) { int k = i >> 5, j = i & 31; WS[OFF_MSG1T + i] = msg_W1[j * 67 + k]; }
    for (int i = t; i < 1024; i += 256)    { int k = i >> 5, j = i & 31; WS[OFF_MSG2T + i] = msg_W2[j * 32 + k]; }
    for (int i = t; i < 2048; i += 256) {
        int k = i >> 5, j = i & 31;
        WS[OFF_GR + i] = (k < 32) ? w_ih[j * 32 + k]          : w_hh[j * 32 + (k - 32)];
        WS[OFF_GZ + i] = (k < 32) ? w_ih[(32 + j) * 32 + k]   : w_hh[(32 + j) * 32 + (k - 32)];
        WS[OFF_GN + i] = (k < 32) ? w_ih[(64 + j) * 32 + k]   : w_hh[(64 + j) * 32 + (k - 32)];
    }
    if (t < 32) {
        WS[OFF_BR + t] = b_ih[t] + b_hh[t];
        WS[OFF_BZ + t] = b_ih[32 + t] + b_hh[32 + t];
    }
    for (int i = t; i < 1024; i += 256) {  // WcT[k][j] = sum_o Wo[j][o]*Wv[o][k]
        int k = i >> 5, j = i & 31;
        float a = 0.0f;
        for (int o = 0; o < 32; ++o) a += Wo[j * 32 + o] * Wv[o * 32 + k];
        WS[OFF_WC + i] = a;
    }
    if (t < 32) {
        float a = bo[t];
        for (int o = 0; o < 32; ++o) a += Wo[t * 32 + o] * bv[o];
        WS[OFF_BC + t] = a;
    }
    for (int i = t; i < 34 * 32; i += 256) { int k = i >> 5, j = i & 31; WS[OFF_E1 + i] = emb_W1[j * 34 + k]; }
    for (int i = t; i < 1024; i += 256)    { int k = i >> 5, j = i & 31; WS[OFF_E2 + i] = emb_W2[j * 32 + k]; }
    for (int i = t; i < 1024; i += 256)    { int k = i >> 5, j = i & 31; WS[OFF_C1 + i] = cls_W1[j * 32 + k]; }
}

__global__ __launch_bounds__(BLK) void tgn_fused(
    const int* __restrict__ src_ids, const int* __restrict__ dst_ids,
    const float* __restrict__ edge_feat, const float* __restrict__ delta_t,
    const float* __restrict__ memory,
    const float* __restrict__ msg_b1, const float* __restrict__ msg_b2,
    const float* __restrict__ gru_b_ih, const float* __restrict__ gru_b_hh,
    const float* __restrict__ emb_b1, const float* __restrict__ emb_b2,
    const float* __restrict__ cls_b1, const float* __restrict__ cls_b2,
    const float* __restrict__ cls_W2,
    const float* __restrict__ WS, const int* __restrict__ winner,
    float* __restrict__ probs, float* __restrict__ out_mem, int E, int N) {
    __shared__ float xs[64 * BLK];  // [k][tid] : bank = tid%32, conflict-free
    int bid = blockIdx.x, tid = threadIdx.x;
    int r3 = bid % 3;

    if (r3 == 2) {  // ---- copy worker: non-winner rows of memory -> out_mem ----
        int cw = bid / 3;
        const float4* m4 = (const float4*)memory;
        float4* o4 = (float4*)out_mem;
        int total4 = N * 8;
        for (int i = cw * BLK + tid; i < total4; i += COPY_WORKERS * BLK) {
            int row = i >> 3;
            if (winner[row] == 0) o4[i] = m4[i];
        }
        return;
    }

    // ---- edge worker ----
    int wid = (bid / 3) * 2 + r3;  // 0..4095
    float* xcol = &xs[tid];
    const float4* m4 = (const float4*)memory;

    for (int e = wid * BLK + tid; e < E; e += EDGE_WORKERS * BLK) {
        int src = src_ids[e], dst = dst_ids[e];
        bool win = (winner[dst] == e + 1);
        float2 ef = ((const float2*)edge_feat)[e];
        float dt = delta_t[e];

        // stage x = [src_mem(0..31), dst_mem(32..63)] into own LDS column
#pragma unroll
        for (int i = 0; i < 8; ++i) {
            float4 v = m4[(size_t)src * 8 + i];
            xcol[(4 * i + 0) * 128] = v.x; xcol[(4 * i + 1) * 128] = v.y;
            xcol[(4 * i + 2) * 128] = v.z; xcol[(4 * i + 3) * 128] = v.w;
        }
#pragma unroll
        for (int i = 0; i < 8; ++i) {
            float4 v = m4[(size_t)dst * 8 + i];
            xcol[(32 + 4 * i + 0) * 128] = v.x; xcol[(32 + 4 * i + 1) * 128] = v.y;
            xcol[(32 + 4 * i + 2) * 128] = v.z; xcol[(32 + 4 * i + 3) * 128] = v.w;
        }

        float acc[32];
        // ---- msg layer 1: relu(W1 @ [sm,dm,ef,dt] + b1) ----
#pragma unroll
        for (int j = 0; j < 32; ++j) acc[j] = msg_b1[j];
        pass<0, 64>(acc, WS + OFF_MSG1T, xcol);
        {
            const float* wa = WS + OFF_MSG1T + 64 * 32;
            const float* wb = WS + OFF_MSG1T + 65 * 32;
            const float* wc = WS + OFF_MSG1T + 66 * 32;
#pragma unroll
            for (int j = 0; j < 32; ++j)
                acc[j] = fmaf(ef.x, wa[j], fmaf(ef.y, wb[j], fmaf(dt, wc[j], acc[j])));
        }
#pragma unroll
        for (int j = 0; j < 32; ++j) xcol[j * 128] = fmaxf(acc[j], 0.0f);  // h -> rows 0..31

        // ---- msg layer 2 ----
#pragma unroll
        for (int j = 0; j < 32; ++j) acc[j] = msg_b2[j];
        pass<0, 32>(acc, WS + OFF_MSG2T, xcol);
#pragma unroll
        for (int j = 0; j < 32; ++j) xcol[j * 128] = acc[j];  // msg -> rows 0..31

        // ---- GRU r,z over concat [msg(0..31), dm(32..63)] ----
        float r_[32];
#pragma unroll
        for (int j = 0; j < 32; ++j) r_[j] = WS[OFF_BR + j];
        pass<0, 64>(r_, WS + OFF_GR, xcol);
#pragma unroll
        for (int j = 0; j < 32; ++j) r_[j] = sigf(r_[j]);
        float z_[32];
#pragma unroll
        for (int j = 0; j < 32; ++j) z_[j] = WS[OFF_BZ + j];
        pass<0, 64>(z_, WS + OFF_GZ, xcol);
#pragma unroll
        for (int j = 0; j < 32; ++j) z_[j] = sigf(z_[j]);
        // ---- GRU n: h_n = b_hh + Whh@dm ; acc = b_ih + r*h_n ; acc += Wih@msg ----
#pragma unroll
        for (int j = 0; j < 32; ++j) acc[j] = gru_b_hh[64 + j];
        pass<32, 64>(acc, WS + OFF_GN + 32 * 32, xcol);
#pragma unroll
        for (int j = 0; j < 32; ++j) acc[j] = fmaf(r_[j], acc[j], gru_b_ih[64 + j]);
        pass<0, 32>(acc, WS + OFF_GN, xcol);
        float u[32];
#pragma unroll
        for (int j = 0; j < 32; ++j) {
            float n = tanhf_fast(acc[j]);
            float dmv = xcol[(32 + j) * 128];
            u[j] = n + z_[j] * (dmv - n);  // (1-z)*n + z*dm
        }
        if (win) {
            float4* orow = (float4*)(out_mem + (size_t)dst * 32);
#pragma unroll
            for (int i = 0; i < 8; ++i)
                orow[i] = make_float4(u[4 * i], u[4 * i + 1], u[4 * i + 2], u[4 * i + 3]);
        }

        // ---- attn (folded to one 32x32) over dm ----
#pragma unroll
        for (int j = 0; j < 32; ++j) acc[j] = WS[OFF_BC + j];
        pass<32, 64>(acc, WS + OFF_WC, xcol);
#pragma unroll
        for (int j = 0; j < 32; ++j) xcol[j * 128] = acc[j];  // at -> rows 0..31

        // ---- emb layer 1: relu(E1 @ [at, ef]) ----
#pragma unroll
        for (int j = 0; j < 32; ++j) acc[j] = emb_b1[j];
        pass<0, 32>(acc, WS + OFF_E1, xcol);
        {
            const float* wa = WS + OFF_E1 + 32 * 32;
            const float* wb = WS + OFF_E1 + 33 * 32;
#pragma unroll
            for (int j = 0; j < 32; ++j) acc[j] = fmaf(ef.x, wa[j], fmaf(ef.y, wb[j], acc[j]));
        }
#pragma unroll
        for (int j = 0; j < 32; ++j) xcol[j * 128] = fmaxf(acc[j], 0.0f);

        // ---- emb layer 2 ----
#pragma unroll
        for (int j = 0; j < 32; ++j) acc[j] = emb_b2[j];
        pass<0, 32>(acc, WS + OFF_E2, xcol);
#pragma unroll
        for (int j = 0; j < 32; ++j) xcol[j * 128] = acc[j];

        // ---- cls layer 1 (keep in regs) + logit ----
#pragma unroll
        for (int j = 0; j < 32; ++j) acc[j] = cls_b1[j];
        pass<0, 32>(acc, WS + OFF_C1, xcol);
#pragma unroll
        for (int j = 0; j < 32; ++j) acc[j] = fmaxf(acc[j], 0.0f);
        float lg = cls_b2[0];
#pragma unroll
        for (int k = 0; k < 32; ++k) lg = fmaf(acc[k], cls_W2[k], lg);
        probs[e] = sigf(lg);
    }
}

extern "C" void kernel_launch(void* const* d_in, const int* in_sizes, int n_in,
                              void* d_out, int out_size, void* d_ws, size_t ws_size,
                              hipStream_t stream) {
    const int*   src_ids   = (const int*)d_in[0];
    const int*   dst_ids   = (const int*)d_in[1];
    const float* edge_feat = (const float*)d_in[2];
    const float* delta_t   = (const float*)d_in[3];
    const float* memory    = (const float*)d_in[4];
    const float* msg_W1 = (const float*)d_in[5],  *msg_b1 = (const float*)d_in[6];
    const float* msg_W2 = (const float*)d_in[7],  *msg_b2 = (const float*)d_in[8];
    const float* w_ih   = (const float*)d_in[9],  *b_ih   = (const float*)d_in[10];
    const float* w_hh   = (const float*)d_in[11], *b_hh   = (const float*)d_in[12];
    const float* Wv     = (const float*)d_in[13], *bv     = (const float*)d_in[14];
    const float* Wo     = (const float*)d_in[15], *bo     = (const float*)d_in[16];
    const float* emb_W1 = (const float*)d_in[17], *emb_b1 = (const float*)d_in[18];
    const float* emb_W2 = (const float*)d_in[19], *emb_b2 = (const float*)d_in[20];
    const float* cls_W1 = (const float*)d_in[21], *cls_b1 = (const float*)d_in[22];
    const float* cls_W2 = (const float*)d_in[23], *cls_b2 = (const float*)d_in[24];

    int E = in_sizes[0];
    int N = in_sizes[4] / 32;

    int*   winner = (int*)d_ws;
    float* WS     = (float*)((char*)d_ws + (size_t)N * sizeof(int));
    float* probs  = (float*)d_out;
    float* outmem = probs + E;

    hipMemsetAsync(winner, 0, (size_t)N * sizeof(int), stream);
    winner_k<<<(E + 255) / 256, 256, 0, stream>>>(dst_ids, winner, E);
    prep_k<<<1, 256, 0, stream>>>(msg_W1, msg_W2, w_ih, b_ih, w_hh, b_hh,
                                  Wv, bv, Wo, bo, emb_W1, emb_W2, cls_W1, WS);
    tgn_fused<<<EDGE_WORKERS / 2 * 3, BLK, 0, stream>>>(
        src_ids, dst_ids, edge_feat, delta_t, memory,
        msg_b1, msg_b2, b_ih, b_hh, emb_b1, emb_b2, cls_b1, cls_b2, cls_W2,
        WS, winner, probs, outmem, E, N);
}